// Round 1
// baseline (715.005 us; speedup 1.0000x reference)
//
#include <hip/hip_runtime.h>

#define TOKENS 8192
#define HIDDEN 2048
#define INTER  5632

typedef _Float16 f16x8 __attribute__((ext_vector_type(8)));
typedef float    f32x4 __attribute__((ext_vector_type(4)));

// async global->LDS, 16B per lane. LDS dest = wave-uniform base + lane*16.
__device__ __forceinline__ void async_copy16(const void* g, void* l) {
  __builtin_amdgcn_global_load_lds(
      (const __attribute__((address_space(1))) unsigned int*)g,
      (__attribute__((address_space(3))) unsigned int*)l, 16, 0, 0);
}

// x [T,H] fp32 -> staged [T/128][H/8][128][8] f16
__global__ void k_convert_x(const float* __restrict__ x, _Float16* __restrict__ xs) {
  const int kb = blockIdx.x;            // H/8 = 256
  const int mt = blockIdx.y;            // T/128 = 64
  const int m  = threadIdx.x;           // 128
  const float* src = x + (size_t)(mt * 128 + m) * HIDDEN + kb * 8;
  float4 f0 = *(const float4*)src;
  float4 f1 = *(const float4*)(src + 4);
  f16x8 v;
  v[0] = (_Float16)f0.x; v[1] = (_Float16)f0.y; v[2] = (_Float16)f0.z; v[3] = (_Float16)f0.w;
  v[4] = (_Float16)f1.x; v[5] = (_Float16)f1.y; v[6] = (_Float16)f1.z; v[7] = (_Float16)f1.w;
  *(f16x8*)(xs + ((size_t)(mt * 256 + kb) * 128 + m) * 8) = v;
}

// GPTQ dequant: qweight [K/8,N] int32 -> staged [K/8][N][8] f16
// w = (q - (z+1)) * scale ; group = 128 k-rows = 16 k8-rows
__global__ void k_dequant(const unsigned int* __restrict__ qw,
                          const unsigned int* __restrict__ qz,
                          const float* __restrict__ sc,
                          _Float16* __restrict__ out, int N, int N8) {
  const int n  = blockIdx.x * 256 + threadIdx.x;
  const int k8 = blockIdx.y;
  const int g  = k8 >> 4;
  unsigned int q  = qw[(size_t)k8 * N + n];
  unsigned int zw = qz[(size_t)g * N8 + (n >> 3)];
  int   z1 = (int)((zw >> ((n & 7) * 4)) & 0xFu) + 1;
  float s  = sc[(size_t)g * N + n];
  f16x8 w;
#pragma unroll
  for (int j = 0; j < 8; ++j)
    w[j] = (_Float16)((float)((int)((q >> (4 * j)) & 0xFu) - z1) * s);
  *(f16x8*)(out + ((size_t)k8 * N + n) * 8) = w;
}

// GEMM1: h = silu(x@Wg) * (x@Wu), writes h in staged [T/128][I/8][128][8] f16
// block: 256 thr = 4 waves (2x2), tile 128x128, BK=64, MFMA 16x16x32 f16
__global__ __launch_bounds__(256, 2)
void k_gemm_gateup(const _Float16* __restrict__ xs,
                   const _Float16* __restrict__ wg,
                   const _Float16* __restrict__ wu,
                   _Float16* __restrict__ hs) {
  __shared__ _Float16 lds[3 * 8192];    // A | Bg | Bu, each [8 kb][128][8] = 16KB
  _Float16* Al  = lds;
  _Float16* Bgl = lds + 8192;
  _Float16* Bul = lds + 16384;
  const int nt = blockIdx.x, mt = blockIdx.y;
  const int tid = threadIdx.x;
  const int wave = tid >> 6, lane = tid & 63;
  const int wm = wave >> 1, wn = wave & 1;
  const int row16 = lane >> 4, col = lane & 15;
  const int slot = wave * 4;

  const _Float16* gA = xs + (size_t)mt * 256 * 1024;   // + kit*8192 per iter

  int afo[4], bfo[4];
#pragma unroll
  for (int i = 0; i < 4; ++i) {
    afo[i] = (row16 * 128 + wm * 64 + i * 16 + col) * 8;
    bfo[i] = (row16 * 128 + wn * 64 + i * 16 + col) * 8;
  }

  const f32x4 zero = {0.f, 0.f, 0.f, 0.f};
  f32x4 accg[4][4], accu[4][4];
#pragma unroll
  for (int i = 0; i < 4; ++i)
#pragma unroll
    for (int j = 0; j < 4; ++j) { accg[i][j] = zero; accu[i][j] = zero; }

  for (int kit = 0; kit < HIDDEN / 64; ++kit) {        // 32 iters
    __syncthreads();                                    // protect LDS reuse
#pragma unroll
    for (int q = 0; q < 4; ++q) {
      const int c = (slot + q) * 64 + lane;             // 16B chunk id in tile
      async_copy16(gA + (size_t)kit * 8192 + (size_t)c * 8,
                   (char*)Al + (size_t)(slot + q) * 1024);
      const int kbl = c >> 7, cc = c & 127;
      const size_t bo = ((size_t)(kit * 8 + kbl) * INTER + nt * 128 + cc) * 8;
      async_copy16(wg + bo, (char*)Bgl + (size_t)(slot + q) * 1024);
      async_copy16(wu + bo, (char*)Bul + (size_t)(slot + q) * 1024);
    }
    __syncthreads();                                    // drains vmcnt(0)
#pragma unroll
    for (int ks = 0; ks < 2; ++ks) {
      const int kadd = ks * 4096;                       // +4 kb rows
      f16x8 af[4], bg[4], bu[4];
#pragma unroll
      for (int i = 0; i < 4; ++i) {
        af[i] = *(const f16x8*)(Al  + kadd + afo[i]);
        bg[i] = *(const f16x8*)(Bgl + kadd + bfo[i]);
        bu[i] = *(const f16x8*)(Bul + kadd + bfo[i]);
      }
#pragma unroll
      for (int mi = 0; mi < 4; ++mi)
#pragma unroll
        for (int ni = 0; ni < 4; ++ni) {
          accg[mi][ni] = __builtin_amdgcn_mfma_f32_16x16x32_f16(af[mi], bg[ni], accg[mi][ni], 0, 0, 0);
          accu[mi][ni] = __builtin_amdgcn_mfma_f32_16x16x32_f16(af[mi], bu[ni], accu[mi][ni], 0, 0, 0);
        }
    }
  }
  // epilogue: h = g*sigmoid(g)*u, scatter into staged layout (2B stores)
#pragma unroll
  for (int mi = 0; mi < 4; ++mi)
#pragma unroll
    for (int ni = 0; ni < 4; ++ni) {
      const int kg = nt * 128 + wn * 64 + ni * 16 + col;   // global INTER idx
      const size_t base = (size_t)(mt * (INTER / 8) + (kg >> 3)) * 1024 + (kg & 7);
#pragma unroll
      for (int r = 0; r < 4; ++r) {
        float g = accg[mi][ni][r], u = accu[mi][ni][r];
        float h = g / (1.f + __expf(-g)) * u;
        const int ml = wm * 64 + mi * 16 + row16 * 4 + r;
        hs[base + (size_t)ml * 8] = (_Float16)h;
      }
    }
}

// GEMM2: out = h @ Wd, fp32 output [T, H]
__global__ __launch_bounds__(256, 2)
void k_gemm_down(const _Float16* __restrict__ hs,
                 const _Float16* __restrict__ wd,
                 float* __restrict__ out) {
  __shared__ _Float16 lds[2 * 8192];
  _Float16* Al = lds;
  _Float16* Bl = lds + 8192;
  const int nt = blockIdx.x, mt = blockIdx.y;
  const int tid = threadIdx.x;
  const int wave = tid >> 6, lane = tid & 63;
  const int wm = wave >> 1, wn = wave & 1;
  const int row16 = lane >> 4, col = lane & 15;
  const int slot = wave * 4;

  const _Float16* gA = hs + (size_t)mt * (INTER / 8) * 1024;

  int afo[4], bfo[4];
#pragma unroll
  for (int i = 0; i < 4; ++i) {
    afo[i] = (row16 * 128 + wm * 64 + i * 16 + col) * 8;
    bfo[i] = (row16 * 128 + wn * 64 + i * 16 + col) * 8;
  }

  const f32x4 zero = {0.f, 0.f, 0.f, 0.f};
  f32x4 acc[4][4];
#pragma unroll
  for (int i = 0; i < 4; ++i)
#pragma unroll
    for (int j = 0; j < 4; ++j) acc[i][j] = zero;

  for (int kit = 0; kit < INTER / 64; ++kit) {          // 88 iters
    __syncthreads();
#pragma unroll
    for (int q = 0; q < 4; ++q) {
      const int c = (slot + q) * 64 + lane;
      async_copy16(gA + (size_t)kit * 8192 + (size_t)c * 8,
                   (char*)Al + (size_t)(slot + q) * 1024);
      const int kbl = c >> 7, cc = c & 127;
      const size_t bo = ((size_t)(kit * 8 + kbl) * HIDDEN + nt * 128 + cc) * 8;
      async_copy16(wd + bo, (char*)Bl + (size_t)(slot + q) * 1024);
    }
    __syncthreads();
#pragma unroll
    for (int ks = 0; ks < 2; ++ks) {
      const int kadd = ks * 4096;
      f16x8 af[4], bf[4];
#pragma unroll
      for (int i = 0; i < 4; ++i) {
        af[i] = *(const f16x8*)(Al + kadd + afo[i]);
        bf[i] = *(const f16x8*)(Bl + kadd + bfo[i]);
      }
#pragma unroll
      for (int mi = 0; mi < 4; ++mi)
#pragma unroll
        for (int ni = 0; ni < 4; ++ni)
          acc[mi][ni] = __builtin_amdgcn_mfma_f32_16x16x32_f16(af[mi], bf[ni], acc[mi][ni], 0, 0, 0);
    }
  }
#pragma unroll
  for (int mi = 0; mi < 4; ++mi)
#pragma unroll
    for (int ni = 0; ni < 4; ++ni) {
      const int n = nt * 128 + wn * 64 + ni * 16 + col;
#pragma unroll
      for (int r = 0; r < 4; ++r) {
        const int m = mt * 128 + wm * 64 + mi * 16 + row16 * 4 + r;
        out[(size_t)m * HIDDEN + n] = acc[mi][ni][r];
      }
    }
}

extern "C" void kernel_launch(void* const* d_in, const int* in_sizes, int n_in,
                              void* d_out, int out_size, void* d_ws, size_t ws_size,
                              hipStream_t stream) {
  (void)in_sizes; (void)n_in; (void)out_size; (void)ws_size;
  const float*        x  = (const float*)d_in[0];
  const unsigned int* gq = (const unsigned int*)d_in[1];
  const unsigned int* gz = (const unsigned int*)d_in[2];
  const float*        gs = (const float*)d_in[3];
  const unsigned int* uq = (const unsigned int*)d_in[4];
  const unsigned int* uz = (const unsigned int*)d_in[5];
  const float*        us = (const float*)d_in[6];
  const unsigned int* dq = (const unsigned int*)d_in[7];
  const unsigned int* dz = (const unsigned int*)d_in[8];
  const float*        ds = (const float*)d_in[9];
  float* out = (float*)d_out;

  // workspace layout (bytes):
  // xs  [0, 32MB)   x staged f16
  // wgd [32MB, +22MB) wud [+22MB) wdd [+22MB)  dequanted weights, staged f16
  // hs  [+88MB)     h staged f16   -> total ~186MB
  char* ws = (char*)d_ws;
  _Float16* xs  = (_Float16*)ws;
  _Float16* wgd = (_Float16*)(ws + (size_t)TOKENS * HIDDEN * 2);
  _Float16* wud = wgd + (size_t)HIDDEN * INTER;
  _Float16* wdd = wud + (size_t)HIDDEN * INTER;
  _Float16* hs  = wdd + (size_t)INTER * HIDDEN;

  k_convert_x<<<dim3(HIDDEN / 8, TOKENS / 128), 128, 0, stream>>>(x, xs);
  k_dequant<<<dim3(INTER / 256, HIDDEN / 8), 256, 0, stream>>>(gq, gz, gs, wgd, INTER, INTER / 8);
  k_dequant<<<dim3(INTER / 256, HIDDEN / 8), 256, 0, stream>>>(uq, uz, us, wud, INTER, INTER / 8);
  k_dequant<<<dim3(HIDDEN / 256, INTER / 8), 256, 0, stream>>>(dq, dz, ds, wdd, HIDDEN, HIDDEN / 8);
  k_gemm_gateup<<<dim3(INTER / 128, TOKENS / 128), 256, 0, stream>>>(xs, wgd, wud, hs);
  k_gemm_down<<<dim3(HIDDEN / 128, TOKENS / 128), 256, 0, stream>>>(hs, wdd, out);
}